// Round 22
// baseline (122.730 us; speedup 1.0000x reference)
//
#include <hip/hip_runtime.h>

#define B_    2
#define N_    2048
#define EMBED 896
#define HQ    16
#define HK    4
#define D_    56
#define DP    64

typedef unsigned short u16;
typedef unsigned int   u32;
typedef __attribute__((ext_vector_type(8))) short bf16x8;
typedef __attribute__((ext_vector_type(4))) short bf16x4;
typedef __attribute__((ext_vector_type(4))) float f32x4;

__device__ __forceinline__ u16 f2bf(float f) {
  u32 u = __builtin_bit_cast(u32, f);
  return (u16)((u + 0x7FFFu + ((u >> 16) & 1u)) >> 16);
}

__device__ __forceinline__ float bf2f(u16 x) {
  u32 u = (u32)x << 16;
  return __builtin_bit_cast(float, u);
}

// pack 2 f32 -> 2 bf16 in one u32 (RNE), single VALU op
__device__ __forceinline__ u32 cvtpk_bf16(float lo, float hi) {
  u32 r;
  asm("v_cvt_pk_bf16_f32 %0, %1, %2" : "=v"(r) : "v"(lo), "v"(hi));
  return r;
}

#define EXP2F(x) __builtin_amdgcn_exp2f(x)

// Async global->LDS, 16B per lane. LDS dest is wave-uniform base + lane*16.
__device__ __forceinline__ void gload_lds16(const u16* g, u16* l) {
  __builtin_amdgcn_global_load_lds(
      (const __attribute__((address_space(1))) void*)g,
      (__attribute__((address_space(3))) void*)l, 16, 0, 0);
}

// QSCALE = (1/sqrt(56)) * log2(e); folded into Q so softmax uses exp2
#define QSCALE 0.19278822f

// ---------------------------------------------------------------------------
// Zero pad lanes: Qf fragment-major pad chunks (cols 56..63 = kk=1, fg=3),
// Kp rows d=56..63, Vt pad stripes. 1.57 MB, one int4/thread.
// ---------------------------------------------------------------------------
__global__ __launch_bounds__(256) void pad_zero(u16* __restrict__ Qf,
                                                u16* __restrict__ Kp,
                                                u16* __restrict__ Vt) {
  int i = blockIdx.x * 256 + threadIdx.x;  // 0..98303
  int4 z = {0, 0, 0, 0};
  if (i < 65536) {                       // Qf pad chunks: 1024 tiles x 4 ifr x 16 fr
    int tile = i >> 6, ifr = (i >> 4) & 3, fr = i & 15;
    *(int4*)(Qf + (size_t)tile * 4096 +
             ((((ifr * 2 + 1) * 4 + 3) * 16) + fr) * 8) = z;
  } else if (i < 81920) {                // Kp rows (b*HK*N)
    *(int4*)(Kp + (size_t)(i - 65536) * 64 + 56) = z;
  } else {                               // Vt pad stripes: 8 x (8 rows x 2048)
    int j = i - 81920;                   // 0..16383
    int bhk = j >> 11;                   // 0..7
    int off = j & 2047;                  // int4 index within stripe
    *(int4*)(Vt + ((size_t)bhk * 64 + 56) * 2048 + (size_t)off * 8) = z;
  }
}

// ---------------------------------------------------------------------------
// Bulk f32 -> bf16 conversion, 4 float4/thread (ILP=4).
// grid 3178 x 256 covers 3,254,272 float4s exactly.
// ---------------------------------------------------------------------------
#define SEG_IN  3670016u   // 2*2048*896
#define SEG_WQ  802816u    // 896*896
#define SEG_WK  200704u    // 224*896

__global__ __launch_bounds__(256) void to_bf16(
    const float* __restrict__ q, const float* __restrict__ k,
    const float* __restrict__ v, const float* __restrict__ wq,
    const float* __restrict__ wk, const float* __restrict__ wv,
    const float* __restrict__ wo, u16* __restrict__ qb, u16* __restrict__ kb,
    u16* __restrict__ vb, u16* __restrict__ wqb, u16* __restrict__ wkb,
    u16* __restrict__ wvb, u16* __restrict__ wob) {
  const size_t base = (size_t)blockIdx.x * 1024 + threadIdx.x;
  float4 v4[4];
  u16* dsts[4];
  size_t offs[4];
#pragma unroll
  for (int j = 0; j < 4; j++) {
    size_t e = (base + j * 256) * 4;
    const float* src;
    u16* dst;
    size_t off;
    if (e < SEG_IN)                  { src = q;  dst = qb;  off = e; }
    else if (e < 2 * (size_t)SEG_IN) { src = k;  dst = kb;  off = e - SEG_IN; }
    else if (e < 3 * (size_t)SEG_IN) { src = v;  dst = vb;  off = e - 2 * (size_t)SEG_IN; }
    else {
      size_t r = e - 3 * (size_t)SEG_IN;
      if (r < SEG_WQ)                   { src = wq; dst = wqb; off = r; }
      else if (r < SEG_WQ + SEG_WK)     { src = wk; dst = wkb; off = r - SEG_WQ; }
      else if (r < SEG_WQ + 2 * SEG_WK) { src = wv; dst = wvb; off = r - SEG_WQ - SEG_WK; }
      else                              { src = wo; dst = wob; off = r - SEG_WQ - 2 * SEG_WK; }
    }
    dsts[j] = dst; offs[j] = off;
    v4[j] = *(const float4*)(src + off);  // 4 independent loads in flight
  }
#pragma unroll
  for (int j = 0; j < 4; j++) {
    uint2 pb;
    pb.x = cvtpk_bf16(v4[j].x, v4[j].y);
    pb.y = cvtpk_bf16(v4[j].z, v4[j].w);
    *(uint2*)(dsts[j] + offs[j]) = pb;
  }
}

// ---------------------------------------------------------------------------
// GEMM core (m97 structure): BM=128, BN=64, BK=64, 256 thr. Single-buffer
// linear LDS staged via global_load_lds width=16. XOR swizzle both sides.
// ---------------------------------------------------------------------------
#define NT_K 14  // 896/64

#define GEMM_CORE(APTR, WPTR)                                                  \
  for (int it = 0; it < NT_K; ++it) {                                          \
    const int k0 = it * 64;                                                    \
    {                                                                          \
      const u16* Ag = (APTR) + (size_t)m0 * EMBED + k0;                        \
      _Pragma("unroll") for (int i = 0; i < 4; i++) {                          \
        int f = i * 256 + t;                                                   \
        int r = f >> 3, s = (f & 7) ^ (r & 7);                                 \
        gload_lds16(Ag + (size_t)r * EMBED + s * 8,                            \
                    AsL + (i * 256 + fwbase) * 8);                             \
      }                                                                        \
      const u16* Wg = (WPTR) + (size_t)wn0 * EMBED + k0;                       \
      _Pragma("unroll") for (int i = 0; i < 2; i++) {                          \
        int f = i * 256 + t;                                                   \
        int r = f >> 3, s = (f & 7) ^ (r & 7);                                 \
        gload_lds16(Wg + (size_t)r * EMBED + s * 8,                            \
                    BsL + (i * 256 + fwbase) * 8);                             \
      }                                                                        \
    }                                                                          \
    __syncthreads(); /* drains vmcnt -> staged data visible */                 \
    _Pragma("unroll") for (int kk = 0; kk < 2; kk++) {                         \
      bf16x8 af[2], bfv[4];                                                    \
      _Pragma("unroll") for (int mf = 0; mf < 2; mf++) {                       \
        int ra = wr + mf * 16 + fr;                                            \
        af[mf] =                                                               \
            *(const bf16x8*)&AsL[ra * 64 + ((fg + kk * 4) ^ (ra & 7)) * 8];    \
      }                                                                        \
      _Pragma("unroll") for (int nf = 0; nf < 4; nf++) {                       \
        int rb = nf * 16 + fr;                                                 \
        bfv[nf] =                                                              \
            *(const bf16x8*)&BsL[rb * 64 + ((fg + kk * 4) ^ (rb & 7)) * 8];    \
      }                                                                        \
      _Pragma("unroll") for (int mf = 0; mf < 2; mf++)                         \
          _Pragma("unroll") for (int nf = 0; nf < 4; nf++)                     \
              acc[mf][nf] = __builtin_amdgcn_mfma_f32_16x16x32_bf16(           \
                  af[mf], bfv[nf], acc[mf][nf], 0, 0, 0);                      \
    }                                                                          \
    __syncthreads(); /* all waves done reading before next overwrite */       \
  }

// Fused QKV projection. r22: reverted to 2D grid (32,22) — the r21 XCD
// swizzle RAISED FETCH 20->35MB (each XCD re-read all of A). Q scatters
// directly into fragment-major Qf.
__global__ __launch_bounds__(256) void proj_gemm(
    const u16* __restrict__ qb, const u16* __restrict__ kb,
    const u16* __restrict__ vb, const u16* __restrict__ Wqb,
    const u16* __restrict__ Wkb, const u16* __restrict__ Wvb,
    u16* __restrict__ Qf, u16* __restrict__ Kp, u16* __restrict__ Vt) {
  __shared__ __align__(16) u16 lds[12288];  // AsL 128x64 | BsL 64x64
  u16* AsL = lds;
  u16* BsL = lds + 8192;
  const int t = threadIdx.x;
  const int m0 = blockIdx.x * 128;
  const int y = blockIdx.y;
  int p, nt;
  if (y < 14)      { p = 0; nt = y; }
  else if (y < 18) { p = 1; nt = y - 14; }
  else             { p = 2; nt = y - 18; }
  const u16* A = p == 0 ? qb : (p == 1 ? kb : vb);
  const u16* W = p == 0 ? Wqb : (p == 1 ? Wkb : Wvb);
  const int Nproj = p == 0 ? 896 : 224;
  const int wn0 = nt * 64;

  const int w = t >> 6, lane = t & 63;
  const int fr = lane & 15, fg = lane >> 4;
  const int wr = w * 32;
  const int fwbase = t & 192;  // w*64, wave-uniform

  f32x4 acc[2][4] = {};

  GEMM_CORE(A, W)

  if (p == 0) {
    // Q: scatter into fragment-major Qf with QSCALE
#pragma unroll
    for (int nf = 0; nf < 4; nf++) {
      int col = wn0 + nf * 16 + fr;  // < 896 always
      int hh = col / 56, d = col - hh * 56;
      int kkq = d >> 5, fgq = (d & 31) >> 3, c7 = d & 7;
#pragma unroll
      for (int mf = 0; mf < 2; mf++)
#pragma unroll
        for (int r = 0; r < 4; r++) {
          int row = m0 + wr + mf * 16 + fg * 4 + r;
          int bb = row >> 11, nn = row & 2047;
          int tile = (bb * 16 + hh) * 32 + (nn >> 6);
          int irow = nn & 63, ifr = irow >> 4, frq = irow & 15;
          Qf[(size_t)tile * 4096 +
             ((((ifr * 2 + kkq) * 4 + fgq) * 16) + frq) * 8 + c7] =
              f2bf(acc[mf][nf][r] * QSCALE);
        }
    }
  } else if (p == 1) {
#pragma unroll
    for (int nf = 0; nf < 4; nf++) {
      int col = wn0 + nf * 16 + fr;
      if (col < Nproj) {
        int hh = col / 56, d = col - hh * 56;
#pragma unroll
        for (int mf = 0; mf < 2; mf++)
#pragma unroll
          for (int r = 0; r < 4; r++) {
            int row = m0 + wr + mf * 16 + fg * 4 + r;
            int bb = row >> 11, nn = row & 2047;
            Kp[((size_t)((bb * 4 + hh) * 2048 + nn)) * 64 + d] =
                f2bf(acc[mf][nf][r]);
          }
      }
    }
  } else {
    // V: transpose through LDS (reuse staging buffer), coalesced int4 stores
    u16* Traw = lds;  // need 64*136 = 8704 <= 12288
#define TS(r_, c_) Traw[(r_)*136 + (c_)]
#pragma unroll
    for (int nf = 0; nf < 4; nf++)
#pragma unroll
      for (int mf = 0; mf < 2; mf++)
#pragma unroll
        for (int r = 0; r < 4; r++)
          TS(nf * 16 + fr, wr + mf * 16 + fg * 4 + r) = f2bf(acc[mf][nf][r]);
    __syncthreads();
    const int bb = m0 >> 11, n_base = m0 & 2047;
#pragma unroll
    for (int i = 0; i < 4; i++) {
      int flat = i * 256 + t;     // 0..1023
      int dr = flat >> 4;         // 0..63 (local V col)
      int c8 = (flat & 15) * 8;   // 0..120 (local row)
      int col = wn0 + dr;
      if (col < 224) {
        int hh = col / 56, d = col - hh * 56;
        *(int4*)(Vt + ((size_t)((bb * 4 + hh) * 64 + d)) * 2048 + n_base + c8) =
            *(int4*)&TS(dr, c8);
      }
    }
  }
}

// Output projection: out = LNo (bf16) @ Wo^T. 1D grid 448 = 8 XCD x 56,
// XCD-grouping swizzle (blocks sharing a W panel cluster per XCD).
__global__ __launch_bounds__(256) void gemm_wo(const u16* __restrict__ A,
                                               const u16* __restrict__ W,
                                               float* __restrict__ C) {
  __shared__ __align__(16) u16 lds[12288];
  u16* AsL = lds;
  u16* BsL = lds + 8192;
  const int t = threadIdx.x;
  const int bid = blockIdx.x;            // 0..447
  const int lin = (bid & 7) * 56 + (bid >> 3);
  const int m0 = (lin & 31) * 128;
  const int wn0 = (lin >> 5) * 64;       // panel 0..13
  const int w = t >> 6, lane = t & 63;
  const int fr = lane & 15, fg = lane >> 4;
  const int wr = w * 32;
  const int fwbase = t & 192;

  f32x4 acc[2][4] = {};

  GEMM_CORE(A, W)

#pragma unroll
  for (int nf = 0; nf < 4; nf++) {
    int col = wn0 + nf * 16 + fr;
#pragma unroll
    for (int mf = 0; mf < 2; mf++)
#pragma unroll
      for (int r = 0; r < 4; r++) {
        int row = m0 + wr + mf * 16 + fg * 4 + r;
        C[(size_t)row * EMBED + col] = acc[mf][nf][r];
      }
  }
}

// ---------------------------------------------------------------------------
// Pass A: causal flash attention, KV-SPLIT (S=2), SWAPPED QK^T (mfma(K,Q) =
// S^T): lane holds P[qrow=fr][kv=jf*16+fg*4+r] — the A-operand of
// v_mfma_f32_16x16x16_bf16 for PV. P never touches LDS. 32KB LDS.
// Q read from fragment-major Qf (coalesced chunk loads).
// ---------------------------------------------------------------------------
__global__ __launch_bounds__(256) void attn_fwd(const u16* __restrict__ Qf,
                                                const u16* __restrict__ Kp,
                                                const u16* __restrict__ Vt,
                                                u16* __restrict__ Op,
                                                float* __restrict__ lp) {
  const int p = blockIdx.x, hk = blockIdx.y;
  const int b = blockIdx.z >> 1, sg = blockIdx.z & 1;
  const int t = threadIdx.x, w = t >> 6, lane = t & 63;
  const int fr = lane & 15, fg = lane >> 4;
  const int h = hk * 4 + w;

  __shared__ __align__(16) u16 KVs[2][2][4096];  // [buf][K|V][64x64] 32KB

  const u16* Qfh = Qf + (size_t)(b * HQ + h) * N_ * DP;
  const u16* Kh = Kp + (size_t)(b * HK + hk) * N_ * DP;
  const u16* Vh = Vt + (size_t)(b * HK + hk) * DP * N_;

  const int fwb = t & 192;  // wave-uniform LDS base part
  const int fx = fr & 7;    // read-side XOR key

#define ISSUE_KV(ntt_, buf_)                                                   \
  do {                                                                         \
    const u16* Kb = Kh + (size_t)(ntt_)*64 * DP;                               \
    const u16* Vb = Vh + (ntt_)*64;                                            \
    _Pragma("unroll") for (int i = 0; i < 2; i++) {                            \
      int f = i * 256 + t;                                                     \
      int r = f >> 3, sl = (f & 7) ^ (r & 7);                                  \
      gload_lds16(Kb + (size_t)r * DP + sl * 8,                                \
                  &KVs[buf_][0][(i * 256 + fwb) * 8]);                         \
      gload_lds16(Vb + (size_t)r * N_ + sl * 8,                                \
                  &KVs[buf_][1][(i * 256 + fwb) * 8]);                         \
    }                                                                          \
  } while (0)

  // per-half tile ranges for this split
  const int s0 = p, s1 = 127 - p;
  const int ntf0 = (s0 >> 2) + 1, ntf1 = (s1 >> 2) + 1;
  const int lo0 = sg ? (ntf0 >> 1) : 0, hi0 = sg ? ntf0 : (ntf0 >> 1);
  const int lo1 = sg ? (ntf1 >> 1) : 0, hi1 = sg ? ntf1 : (ntf1 >> 1);

  int bi = 0;
  if (hi0 > lo0) {
    ISSUE_KV(lo0, 0);
  } else if (hi1 > lo1) {
    ISSUE_KV(lo1, 0);
  }

  for (int half = 0; half < 2; ++half) {
    const int s = half ? s1 : s0;
    const int ntf = half ? ntf1 : ntf0;
    const int lo = half ? lo1 : lo0, hi = half ? hi1 : hi0;

    // Q fragments from fragment-major Qf: tile s>>2, ifr = s&3
    bf16x8 qf[2];
#pragma unroll
    for (int kk = 0; kk < 2; kk++)
      qf[kk] = *(const bf16x8*)(Qfh + ((size_t)(s >> 2) * 512 +
                                       ((s & 3) * 2 + kk) * 64 +
                                       fg * 16 + fr) * 8);

    f32x4 oacc[4] = {};
    float l_lane = 0.f;  // per-lane partial row sum (qrow = fr)

    for (int tt = lo; tt < hi; ++tt) {
      __syncthreads();  // tile tt's loads landed; all waves done with buf^1
      {
        int ntt = -1;
        if (tt + 1 < hi) ntt = tt + 1;
        else if (half == 0 && hi1 > lo1) ntt = lo1;
        if (ntt >= 0) {
          ISSUE_KV(ntt, bi ^ 1);
        }
      }

      // Swapped QK^T: sacc[jf] = K_jf · Q^T ; lane: qrow=fr, kv=jf*16+fg*4+r
      f32x4 sacc[4] = {};
#pragma unroll
      for (int kk = 0; kk < 2; kk++) {
        bf16x8 bk[4];
#pragma unroll
        for (int jf = 0; jf < 4; jf++)
          bk[jf] = *(const bf16x8*)&KVs[bi][0][(jf * 16 + fr) * 64 +
                                               ((kk * 4 + fg) ^ fx) * 8];
#pragma unroll
        for (int jf = 0; jf < 4; jf++)
          sacc[jf] = __builtin_amdgcn_mfma_f32_16x16x32_bf16(
              bk[jf], qf[kk], sacc[jf], 0, 0, 0);
      }

      // exp2 + mask + pack P IN REGISTERS (A-operand of 16x16x16 PV)
      bf16x4 pa[4];
      if (tt == ntf - 1) {
        const int gi = s * 16 + fr;  // qrow
#pragma unroll
        for (int jf = 0; jf < 4; jf++) {
          float pv[4];
#pragma unroll
          for (int r = 0; r < 4; r++) {
            int gj = tt * 64 + jf * 16 + fg * 4 + r;  // kv
            pv[r] = (gj <= gi) ? EXP2F(sacc[jf][r]) : 0.f;
            l_lane += pv[r];
          }
          uint2 pk = {cvtpk_bf16(pv[0], pv[1]), cvtpk_bf16(pv[2], pv[3])};
          pa[jf] = __builtin_bit_cast(bf16x4, pk);
        }
      } else {
#pragma unroll
        for (int jf = 0; jf < 4; jf++) {
          float pv[4];
#pragma unroll
          for (int r = 0; r < 4; r++) {
            pv[r] = EXP2F(sacc[jf][r]);
            l_lane += pv[r];
          }
          uint2 pk = {cvtpk_bf16(pv[0], pv[1]), cvtpk_bf16(pv[2], pv[3])};
          pa[jf] = __builtin_bit_cast(bf16x4, pk);
        }
      }

      // P @ V via 16x16x16 (K=16 per jf block); V from LDS as b64 reads
#pragma unroll
      for (int df = 0; df < 4; df++) {
        const int vrow = (df * 16 + fr) * 64;  // Vs row = d
#pragma unroll
        for (int jf = 0; jf < 4; jf++) {
          bf16x4 bv = *(const bf16x4*)&KVs[bi][1][vrow +
                                                  (((jf * 2 + (fg >> 1)) ^ fx) * 8) +
                                                  (fg & 1) * 4];
          oacc[df] = __builtin_amdgcn_mfma_f32_16x16x16bf16_1k(
              pa[jf], bv, oacc[df], 0, 0, 0);
        }
      }
      bi ^= 1;
    }

    // epilogue: raw partial sums (no normalization — combine happens in ln)
    {
      float v = l_lane;
      v += __shfl_xor(v, 16);
      v += __shfl_xor(v, 32);
      const size_t obase = (((size_t)(sg * 2 + b) * 16 + h) * 2048 + s * 16);
      if (fg == 0) lp[obase + fr] = v;  // lane holds l for qrow = fr
#pragma unroll
      for (int df = 0; df < 4; df++) {
        int d = df * 16 + fr;
        if (d < D_) {
#pragma unroll
          for (int r = 0; r < 4; r++)
            Op[(obase + fg * 4 + r) * 56 + d] = f2bf(oacc[df][r]);
        }
      }
    }
    l_lane = 0.f;
  }
}

// ---------------------------------------------------------------------------
// Pass B: attention-weight column means via transposed scores T = K*Q^T.
// r22: ONE 32-col strip per block -> grid 2048 = 8 blocks/CU (was 1024 with
// strip pairs; blocks were latency-bound, Occupancy 14%). XCD grouping: 64
// strips of one (h,b) per XCD. Direct stores (strip owned by one block).
// ---------------------------------------------------------------------------
struct QTile {
  bf16x8 q[4][2];
  float li[4];
};

#define LOADQ(dst, rt_)                                                        \
  {                                                                            \
    _Pragma("unroll") for (int ifr = 0; ifr < 4; ifr++) {                      \
      _Pragma("unroll") for (int kk = 0; kk < 2; kk++)                         \
          dst.q[ifr][kk] = *(const bf16x8*)(Qfh +                              \
              ((((size_t)(rt_)*4 + ifr) * 2 + kk) * 64 + fg * 16 + fr) * 8);   \
      dst.li[ifr] = linv_h[(rt_)*64 + ifr * 16 + fr];                          \
    }                                                                          \
  }

#define COMPUTET(src, rt_)                                                     \
  {                                                                            \
    f32x4 tacc[2][4] = {};                                                     \
    _Pragma("unroll") for (int kk = 0; kk < 2; kk++)                           \
        _Pragma("unroll") for (int jm = 0; jm < 2; jm++)                       \
        _Pragma("unroll") for (int ifr = 0; ifr < 4; ifr++)                    \
            tacc[jm][ifr] = __builtin_amdgcn_mfma_f32_16x16x32_bf16(           \
                kf[jm][kk], src.q[ifr][kk], tacc[jm][ifr], 0, 0, 0);           \
    if ((rt_) == rt0) {                                                        \
      _Pragma("unroll") for (int jm = 0; jm < 2; jm++)                         \
          _Pragma("unroll") for (int ifr = 0; ifr < 4; ifr++)                  \
          _Pragma("unroll") for (int r = 0; r < 4; r++) {                      \
        int gi = (rt_)*64 + ifr * 16 + fr;                                     \
        int gj = ct * 32 + jm * 16 + fg * 4 + r;                               \
        if (gi >= gj)                                                          \
          s_acc[jm][r] += EXP2F(tacc[jm][ifr][r]) * src.li[ifr];               \
      }                                                                        \
    } else {                                                                   \
      _Pragma("unroll") for (int jm = 0; jm < 2; jm++)                         \
          _Pragma("unroll") for (int ifr = 0; ifr < 4; ifr++)                  \
          _Pragma("unroll") for (int r = 0; r < 4; r++)                        \
              s_acc[jm][r] += EXP2F(tacc[jm][ifr][r]) * src.li[ifr];           \
    }                                                                          \
  }

__global__ __launch_bounds__(256) void attn_aw(const u16* __restrict__ Qf,
                                               const u16* __restrict__ Kp,
                                               const float* __restrict__ linv_g,
                                               float* __restrict__ aw) {
  // XCD grouping: 64 strip-blocks of one (h,b) per XCD. 2048 = 8 x 4 x 64.
  const int bid = blockIdx.x;
  const int xcd = bid & 7, idx = bid >> 3;   // idx 0..255
  const int g = xcd + 8 * (idx >> 6);        // 0..31 = b*16 + h
  const int ct = idx & 63;                   // 32-col strip of T, 0..63
  const int b = g >> 4, h = g & 15;
  const int hk = h >> 2;
  const int t = threadIdx.x, w = t >> 6, lane = t & 63;
  const int fr = lane & 15, fg = lane >> 4;

  __shared__ float red[4][32];  // [wave][jm*16+fg*4+r]

  const u16* Qfh = Qf + (size_t)(b * HQ + h) * N_ * DP;  // fragment-major
  const u16* Kh = Kp + (size_t)(b * HK + hk) * N_ * DP;
  const float* linv_h = linv_g + (size_t)(b * HQ + h) * N_;

  const int rt0 = ct >> 1;

  bf16x8 kf[2][2];
#pragma unroll
  for (int jm = 0; jm < 2; jm++)
#pragma unroll
    for (int kk = 0; kk < 2; kk++)
      kf[jm][kk] = *(const bf16x8*)(Kh + (size_t)(ct * 32 + jm * 16 + fr) * DP +
                                    kk * 32 + fg * 8);

  float s_acc[2][4] = {};
  QTile qa, qb;
  int rt = rt0 + w;  // wave-strided row loop
  if (rt <= 31) {
    LOADQ(qa, rt);
    while (true) {
      if (rt + 4 <= 31) LOADQ(qb, rt + 4);
      COMPUTET(qa, rt);
      rt += 4;
      if (rt > 31) break;
      if (rt + 4 <= 31) LOADQ(qa, rt + 4);
      COMPUTET(qb, rt);
      rt += 4;
      if (rt > 31) break;
    }
  }

  // cross-lane (fr) reduce, park wave-partials in LDS
#pragma unroll
  for (int jm = 0; jm < 2; jm++)
#pragma unroll
    for (int r = 0; r < 4; r++) {
      float v = s_acc[jm][r];
      v += __shfl_xor(v, 1);
      v += __shfl_xor(v, 2);
      v += __shfl_xor(v, 4);
      v += __shfl_xor(v, 8);
      if (fr == 0) red[w][jm * 16 + fg * 4 + r] = v;
    }

  __syncthreads();
  if (w == 0 && fr == 0) {
#pragma unroll
    for (int jm = 0; jm < 2; jm++)
#pragma unroll
      for (int r = 0; r < 4; r++) {
        int idx2 = jm * 16 + fg * 4 + r;
        float v = red[0][idx2] + red[1][idx2] + red[2][idx2] + red[3][idx2];
        int gj = ct * 32 + jm * 16 + fg * 4 + r;
        aw[((size_t)b * N_ + gj) * HQ + h] = v * (1.0f / N_);
      }
  }
}

// ---------------------------------------------------------------------------
// LayerNorm + kv-split COMBINE, one block per (b,n) row:
// x[h*56+d] = (Op0 + Op1) / (l0 + l1); also writes linv for attn_aw.
// bf16 output for the Wo GEMM.
// ---------------------------------------------------------------------------
__global__ __launch_bounds__(256) void ln_fwd(const u16* __restrict__ Op,
                                              const float* __restrict__ lp,
                                              const float* __restrict__ gamma,
                                              const float* __restrict__ beta,
                                              u16* __restrict__ out,
                                              float* __restrict__ linv_g) {
  const int row = blockIdx.x;
  const int b = row >> 11, n = row & 2047;
  const int t = threadIdx.x;
  __shared__ float lrec[16];
  __shared__ float red[8];

  if (t < 16) {
    float l0 = lp[((size_t)(0 + b) * 16 + t) * 2048 + n];
    float l1 = lp[((size_t)(2 + b) * 16 + t) * 2048 + n];
    float ri = 1.0f / (l0 + l1);
    lrec[t] = ri;
    linv_g[((size_t)b * 16 + t) * 2048 + n] = ri;
  }
  __syncthreads();

  float s = 0.f, s2 = 0.f;
  float v[4];
#pragma unroll
  for (int i = 0; i < 4; i++) {
    int c = t + 256 * i;
    if (c < EMBED) {
      int h = c / 56, d = c - h * 56;
      size_t o0 = (((size_t)(0 + b) * 16 + h) * 2048 + n) * 56 + d;
      size_t o1 = (((size_t)(2 + b) * 16 + h) * 2048 + n) * 56 + d;
      v[i] = (bf2f(Op[o0]) + bf2f(Op[o1])) * lrec[h];
    } else {
      v[i] = 0.f;
    }
    s += v[i];
    s2 += v[i] * v[i];
  }
#pragma unroll
  for (int m = 1; m <= 32; m <<= 1) {
    s += __shfl_xor(s, m);
    s2 += __shfl_xor(s2, m);
  }
  const int w = t >> 6, lane = t & 63;
  if (lane == 0) {
    red[w] = s;
    red[4 + w] = s2;
  }
  __syncthreads();
  s = red[0] + red[1] + red[2] + red[3];
  s2 = red[4] + red[5] + red[6] + red[7];
  const float mu = s * (1.0f / EMBED);
  const float var = s2 * (1.0f / EMBED) - mu * mu;
  const float rs = rsqrtf(var + 1e-5f);
#pragma unroll
  for (int i = 0; i < 4; i++) {
    int c = t + 256 * i;
    if (c < EMBED)
      out[(size_t)row * EMBED + c] = f2bf((v[i] - mu) * rs * gamma[c] + beta[c]);
  }
}

// ---------------------------------------------------------------------------
extern "C" void kernel_launch(void* const* d_in, const int* in_sizes, int n_in,
                              void* d_out, int out_size, void* d_ws,
                              size_t ws_size, hipStream_t stream) {
  (void)in_sizes; (void)n_in; (void)out_size; (void)ws_size;
  const float* query = (const float*)d_in[0];
  const float* key   = (const float*)d_in[1];
  const float* value = (const float*)d_in[2];
  const float* Wq    = (const float*)d_in[3];
  const float* Wk    = (const float*)d_in[4];
  const float* Wv    = (const float*)d_in[5];
  const float* Wo    = (const float*)d_in[6];
  const float* gamma = (const float*)d_in[7];
  const float* beta  = (const float*)d_in[8];

  float* out = (float*)d_out;                   // (b, n, EMBED) f32
  float* aw  = out + (size_t)B_ * N_ * EMBED;   // (b, s, HQ)   f32

  char* ws = (char*)d_ws;
  u16* Qf = (u16*)ws;        ws += (size_t)B_ * HQ * N_ * DP * 2;   // 8.39 MB
  u16* Kp = (u16*)ws;        ws += (size_t)B_ * HK * N_ * DP * 2;   // 2.10 MB
  u16* Vt = (u16*)ws;        ws += (size_t)B_ * HK * N_ * DP * 2;   // 2.10 MB
  float* linv = (float*)ws;  ws += (size_t)B_ * HQ * N_ * 4;        // 0.26 MB
  float* lp   = (float*)ws;  ws += (size_t)4 * HQ * N_ * 4;         // 0.52 MB
  u16* Wqb = (u16*)ws;       ws += (size_t)SEG_WQ * 2;              // 1.61 MB
  u16* Wkb = (u16*)ws;       ws += (size_t)SEG_WK * 2;              // 0.40 MB
  u16* Wvb = (u16*)ws;       ws += (size_t)SEG_WK * 2;              // 0.40 MB
  u16* Wob = (u16*)ws;       ws += (size_t)SEG_WQ * 2;              // 1.61 MB
  char* region = ws;         // 22.02 MB region, two lifetimes:
  u16* qb = (u16*)region;                        // phase 1: qb/kb/vb
  u16* kb = qb + (size_t)SEG_IN;
  u16* vb = kb + (size_t)SEG_IN;
  u16* Op  = (u16*)region;                       // phase 2: Op (14.68 MB)
  u16* LNo = Op + (size_t)4 * HQ * N_ * 56;      //          + LNo (7.34 MB)

  dim3 blk(256);
  const int M = B_ * N_;  // 4096

  pad_zero<<<dim3(384), blk, 0, stream>>>(Qf, Kp, Vt);  // 1.57MB

  to_bf16<<<dim3(3178), blk, 0, stream>>>(query, key, value, Wq, Wk, Wv, Wo,
                                          qb, kb, vb, Wqb, Wkb, Wvb, Wob);

  proj_gemm<<<dim3(M / 128, 22), blk, 0, stream>>>(qb, kb, vb, Wqb, Wkb, Wvb,
                                                   Qf, Kp, Vt);

  attn_fwd<<<dim3(64, HK, B_ * 2), blk, 0, stream>>>(Qf, Kp, Vt, Op, lp);
  ln_fwd<<<dim3(M), blk, 0, stream>>>(Op, lp, gamma, beta, LNo, linv);

  attn_aw<<<dim3(2048), blk, 0, stream>>>(Qf, Kp, linv, aw);
  gemm_wo<<<dim3(448), blk, 0, stream>>>(LNo, Wob, out);
}

// Round 24
// 120.038 us; speedup vs baseline: 1.0224x; 1.0224x over previous
//
#include <hip/hip_runtime.h>

#define B_    2
#define N_    2048
#define EMBED 896
#define HQ    16
#define HK    4
#define D_    56
#define DP    64

typedef unsigned short u16;
typedef unsigned int   u32;
typedef __attribute__((ext_vector_type(8))) short bf16x8;
typedef __attribute__((ext_vector_type(4))) short bf16x4;
typedef __attribute__((ext_vector_type(4))) float f32x4;

__device__ __forceinline__ u16 f2bf(float f) {
  u32 u = __builtin_bit_cast(u32, f);
  return (u16)((u + 0x7FFFu + ((u >> 16) & 1u)) >> 16);
}

__device__ __forceinline__ float bf2f(u16 x) {
  u32 u = (u32)x << 16;
  return __builtin_bit_cast(float, u);
}

// pack 2 f32 -> 2 bf16 in one u32 (RNE), single VALU op
__device__ __forceinline__ u32 cvtpk_bf16(float lo, float hi) {
  u32 r;
  asm("v_cvt_pk_bf16_f32 %0, %1, %2" : "=v"(r) : "v"(lo), "v"(hi));
  return r;
}

#define EXP2F(x) __builtin_amdgcn_exp2f(x)

// Async global->LDS, 16B per lane. LDS dest is wave-uniform base + lane*16.
__device__ __forceinline__ void gload_lds16(const u16* g, u16* l) {
  __builtin_amdgcn_global_load_lds(
      (const __attribute__((address_space(1))) void*)g,
      (__attribute__((address_space(3))) void*)l, 16, 0, 0);
}

// r24 hardening: explicit drain of THIS wave's outstanding async loads before
// the barrier. If the compiler already emits vmcnt(0) for __syncthreads this
// is a no-op; if its drain is ever insufficient (r23's intermittent
// post-timing divergence), this closes the stale-LDS-read race.
__device__ __forceinline__ void drain_vmem() {
  asm volatile("s_waitcnt vmcnt(0)" ::: "memory");
}

// QSCALE = (1/sqrt(56)) * log2(e); folded into Q so softmax uses exp2
#define QSCALE 0.19278822f

// ---------------------------------------------------------------------------
// Zero pad lanes: Qf fragment-major pad chunks (cols 56..63 = kk=1, fg=3),
// Kp rows d=56..63, Vt pad stripes. 1.57 MB, one int4/thread.
// ---------------------------------------------------------------------------
__global__ __launch_bounds__(256) void pad_zero(u16* __restrict__ Qf,
                                                u16* __restrict__ Kp,
                                                u16* __restrict__ Vt) {
  int i = blockIdx.x * 256 + threadIdx.x;  // 0..98303
  int4 z = {0, 0, 0, 0};
  if (i < 65536) {                       // Qf pad chunks: 1024 tiles x 4 ifr x 16 fr
    int tile = i >> 6, ifr = (i >> 4) & 3, fr = i & 15;
    *(int4*)(Qf + (size_t)tile * 4096 +
             ((((ifr * 2 + 1) * 4 + 3) * 16) + fr) * 8) = z;
  } else if (i < 81920) {                // Kp rows (b*HK*N)
    *(int4*)(Kp + (size_t)(i - 65536) * 64 + 56) = z;
  } else {                               // Vt pad stripes: 8 x (8 rows x 2048)
    int j = i - 81920;                   // 0..16383
    int bhk = j >> 11;                   // 0..7
    int off = j & 2047;                  // int4 index within stripe
    *(int4*)(Vt + ((size_t)bhk * 64 + 56) * 2048 + (size_t)off * 8) = z;
  }
}

// ---------------------------------------------------------------------------
// Bulk f32 -> bf16 conversion, 4 float4/thread (ILP=4).
// grid 3178 x 256 covers 3,254,272 float4s exactly.
// ---------------------------------------------------------------------------
#define SEG_IN  3670016u   // 2*2048*896
#define SEG_WQ  802816u    // 896*896
#define SEG_WK  200704u    // 224*896

__global__ __launch_bounds__(256) void to_bf16(
    const float* __restrict__ q, const float* __restrict__ k,
    const float* __restrict__ v, const float* __restrict__ wq,
    const float* __restrict__ wk, const float* __restrict__ wv,
    const float* __restrict__ wo, u16* __restrict__ qb, u16* __restrict__ kb,
    u16* __restrict__ vb, u16* __restrict__ wqb, u16* __restrict__ wkb,
    u16* __restrict__ wvb, u16* __restrict__ wob) {
  const size_t base = (size_t)blockIdx.x * 1024 + threadIdx.x;
  float4 v4[4];
  u16* dsts[4];
  size_t offs[4];
#pragma unroll
  for (int j = 0; j < 4; j++) {
    size_t e = (base + j * 256) * 4;
    const float* src;
    u16* dst;
    size_t off;
    if (e < SEG_IN)                  { src = q;  dst = qb;  off = e; }
    else if (e < 2 * (size_t)SEG_IN) { src = k;  dst = kb;  off = e - SEG_IN; }
    else if (e < 3 * (size_t)SEG_IN) { src = v;  dst = vb;  off = e - 2 * (size_t)SEG_IN; }
    else {
      size_t r = e - 3 * (size_t)SEG_IN;
      if (r < SEG_WQ)                   { src = wq; dst = wqb; off = r; }
      else if (r < SEG_WQ + SEG_WK)     { src = wk; dst = wkb; off = r - SEG_WQ; }
      else if (r < SEG_WQ + 2 * SEG_WK) { src = wv; dst = wvb; off = r - SEG_WQ - SEG_WK; }
      else                              { src = wo; dst = wob; off = r - SEG_WQ - 2 * SEG_WK; }
    }
    dsts[j] = dst; offs[j] = off;
    v4[j] = *(const float4*)(src + off);  // 4 independent loads in flight
  }
#pragma unroll
  for (int j = 0; j < 4; j++) {
    uint2 pb;
    pb.x = cvtpk_bf16(v4[j].x, v4[j].y);
    pb.y = cvtpk_bf16(v4[j].z, v4[j].w);
    *(uint2*)(dsts[j] + offs[j]) = pb;
  }
}

// ---------------------------------------------------------------------------
// GEMM core (m97 structure): BM=128, BN=64, BK=64, 256 thr. Single-buffer
// linear LDS staged via global_load_lds width=16. XOR swizzle both sides.
// r24: explicit vmcnt(0) drain before the staging barrier.
// ---------------------------------------------------------------------------
#define NT_K 14  // 896/64

#define GEMM_CORE(APTR, WPTR)                                                  \
  for (int it = 0; it < NT_K; ++it) {                                          \
    const int k0 = it * 64;                                                    \
    {                                                                          \
      const u16* Ag = (APTR) + (size_t)m0 * EMBED + k0;                        \
      _Pragma("unroll") for (int i = 0; i < 4; i++) {                          \
        int f = i * 256 + t;                                                   \
        int r = f >> 3, s = (f & 7) ^ (r & 7);                                 \
        gload_lds16(Ag + (size_t)r * EMBED + s * 8,                            \
                    AsL + (i * 256 + fwbase) * 8);                             \
      }                                                                        \
      const u16* Wg = (WPTR) + (size_t)wn0 * EMBED + k0;                       \
      _Pragma("unroll") for (int i = 0; i < 2; i++) {                          \
        int f = i * 256 + t;                                                   \
        int r = f >> 3, s = (f & 7) ^ (r & 7);                                 \
        gload_lds16(Wg + (size_t)r * EMBED + s * 8,                            \
                    BsL + (i * 256 + fwbase) * 8);                             \
      }                                                                        \
    }                                                                          \
    drain_vmem();                                                              \
    __syncthreads(); /* staged data visible to all waves */                    \
    _Pragma("unroll") for (int kk = 0; kk < 2; kk++) {                         \
      bf16x8 af[2], bfv[4];                                                    \
      _Pragma("unroll") for (int mf = 0; mf < 2; mf++) {                       \
        int ra = wr + mf * 16 + fr;                                            \
        af[mf] =                                                               \
            *(const bf16x8*)&AsL[ra * 64 + ((fg + kk * 4) ^ (ra & 7)) * 8];    \
      }                                                                        \
      _Pragma("unroll") for (int nf = 0; nf < 4; nf++) {                       \
        int rb = nf * 16 + fr;                                                 \
        bfv[nf] =                                                              \
            *(const bf16x8*)&BsL[rb * 64 + ((fg + kk * 4) ^ (rb & 7)) * 8];    \
      }                                                                        \
      _Pragma("unroll") for (int mf = 0; mf < 2; mf++)                         \
          _Pragma("unroll") for (int nf = 0; nf < 4; nf++)                     \
              acc[mf][nf] = __builtin_amdgcn_mfma_f32_16x16x32_bf16(           \
                  af[mf], bfv[nf], acc[mf][nf], 0, 0, 0);                      \
    }                                                                          \
    __syncthreads(); /* all waves done reading before next overwrite */       \
  }

// Fused QKV projection. 2D grid (32,22). Q scatters directly into
// fragment-major Qf.
__global__ __launch_bounds__(256) void proj_gemm(
    const u16* __restrict__ qb, const u16* __restrict__ kb,
    const u16* __restrict__ vb, const u16* __restrict__ Wqb,
    const u16* __restrict__ Wkb, const u16* __restrict__ Wvb,
    u16* __restrict__ Qf, u16* __restrict__ Kp, u16* __restrict__ Vt) {
  __shared__ __align__(16) u16 lds[12288];  // AsL 128x64 | BsL 64x64
  u16* AsL = lds;
  u16* BsL = lds + 8192;
  const int t = threadIdx.x;
  const int m0 = blockIdx.x * 128;
  const int y = blockIdx.y;
  int p, nt;
  if (y < 14)      { p = 0; nt = y; }
  else if (y < 18) { p = 1; nt = y - 14; }
  else             { p = 2; nt = y - 18; }
  const u16* A = p == 0 ? qb : (p == 1 ? kb : vb);
  const u16* W = p == 0 ? Wqb : (p == 1 ? Wkb : Wvb);
  const int Nproj = p == 0 ? 896 : 224;
  const int wn0 = nt * 64;

  const int w = t >> 6, lane = t & 63;
  const int fr = lane & 15, fg = lane >> 4;
  const int wr = w * 32;
  const int fwbase = t & 192;  // w*64, wave-uniform

  f32x4 acc[2][4] = {};

  GEMM_CORE(A, W)

  if (p == 0) {
    // Q: scatter into fragment-major Qf with QSCALE
#pragma unroll
    for (int nf = 0; nf < 4; nf++) {
      int col = wn0 + nf * 16 + fr;  // < 896 always
      int hh = col / 56, d = col - hh * 56;
      int kkq = d >> 5, fgq = (d & 31) >> 3, c7 = d & 7;
#pragma unroll
      for (int mf = 0; mf < 2; mf++)
#pragma unroll
        for (int r = 0; r < 4; r++) {
          int row = m0 + wr + mf * 16 + fg * 4 + r;
          int bb = row >> 11, nn = row & 2047;
          int tile = (bb * 16 + hh) * 32 + (nn >> 6);
          int irow = nn & 63, ifr = irow >> 4, frq = irow & 15;
          Qf[(size_t)tile * 4096 +
             ((((ifr * 2 + kkq) * 4 + fgq) * 16) + frq) * 8 + c7] =
              f2bf(acc[mf][nf][r] * QSCALE);
        }
    }
  } else if (p == 1) {
#pragma unroll
    for (int nf = 0; nf < 4; nf++) {
      int col = wn0 + nf * 16 + fr;
      if (col < Nproj) {
        int hh = col / 56, d = col - hh * 56;
#pragma unroll
        for (int mf = 0; mf < 2; mf++)
#pragma unroll
          for (int r = 0; r < 4; r++) {
            int row = m0 + wr + mf * 16 + fg * 4 + r;
            int bb = row >> 11, nn = row & 2047;
            Kp[((size_t)((bb * 4 + hh) * 2048 + nn)) * 64 + d] =
                f2bf(acc[mf][nf][r]);
          }
      }
    }
  } else {
    // V: transpose through LDS (reuse staging buffer), coalesced int4 stores
    u16* Traw = lds;  // need 64*136 = 8704 <= 12288
#define TS(r_, c_) Traw[(r_)*136 + (c_)]
#pragma unroll
    for (int nf = 0; nf < 4; nf++)
#pragma unroll
      for (int mf = 0; mf < 2; mf++)
#pragma unroll
        for (int r = 0; r < 4; r++)
          TS(nf * 16 + fr, wr + mf * 16 + fg * 4 + r) = f2bf(acc[mf][nf][r]);
    __syncthreads();
    const int bb = m0 >> 11, n_base = m0 & 2047;
#pragma unroll
    for (int i = 0; i < 4; i++) {
      int flat = i * 256 + t;     // 0..1023
      int dr = flat >> 4;         // 0..63 (local V col)
      int c8 = (flat & 15) * 8;   // 0..120 (local row)
      int col = wn0 + dr;
      if (col < 224) {
        int hh = col / 56, d = col - hh * 56;
        *(int4*)(Vt + ((size_t)((bb * 4 + hh) * 64 + d)) * 2048 + n_base + c8) =
            *(int4*)&TS(dr, c8);
      }
    }
  }
}

// Output projection: out = LNo (bf16) @ Wo^T. 1D grid 448 = 8 XCD x 56,
// XCD-grouping swizzle (blocks sharing a W panel cluster per XCD).
__global__ __launch_bounds__(256) void gemm_wo(const u16* __restrict__ A,
                                               const u16* __restrict__ W,
                                               float* __restrict__ C) {
  __shared__ __align__(16) u16 lds[12288];
  u16* AsL = lds;
  u16* BsL = lds + 8192;
  const int t = threadIdx.x;
  const int bid = blockIdx.x;            // 0..447
  const int lin = (bid & 7) * 56 + (bid >> 3);
  const int m0 = (lin & 31) * 128;
  const int wn0 = (lin >> 5) * 64;       // panel 0..13
  const int w = t >> 6, lane = t & 63;
  const int fr = lane & 15, fg = lane >> 4;
  const int wr = w * 32;
  const int fwbase = t & 192;

  f32x4 acc[2][4] = {};

  GEMM_CORE(A, W)

#pragma unroll
  for (int nf = 0; nf < 4; nf++) {
    int col = wn0 + nf * 16 + fr;
#pragma unroll
    for (int mf = 0; mf < 2; mf++)
#pragma unroll
      for (int r = 0; r < 4; r++) {
        int row = m0 + wr + mf * 16 + fg * 4 + r;
        C[(size_t)row * EMBED + col] = acc[mf][nf][r];
      }
  }
}

// ---------------------------------------------------------------------------
// Pass A: causal flash attention, KV-SPLIT (S=2), SWAPPED QK^T (mfma(K,Q) =
// S^T): lane holds P[qrow=fr][kv=jf*16+fg*4+r] — the A-operand of
// v_mfma_f32_16x16x16_bf16 for PV. P never touches LDS. 32KB LDS.
// Q read from fragment-major Qf (coalesced chunk loads).
// r24: explicit vmcnt(0) drain before the per-tile barrier.
// ---------------------------------------------------------------------------
__global__ __launch_bounds__(256) void attn_fwd(const u16* __restrict__ Qf,
                                                const u16* __restrict__ Kp,
                                                const u16* __restrict__ Vt,
                                                u16* __restrict__ Op,
                                                float* __restrict__ lp) {
  const int p = blockIdx.x, hk = blockIdx.y;
  const int b = blockIdx.z >> 1, sg = blockIdx.z & 1;
  const int t = threadIdx.x, w = t >> 6, lane = t & 63;
  const int fr = lane & 15, fg = lane >> 4;
  const int h = hk * 4 + w;

  __shared__ __align__(16) u16 KVs[2][2][4096];  // [buf][K|V][64x64] 32KB

  const u16* Qfh = Qf + (size_t)(b * HQ + h) * N_ * DP;
  const u16* Kh = Kp + (size_t)(b * HK + hk) * N_ * DP;
  const u16* Vh = Vt + (size_t)(b * HK + hk) * DP * N_;

  const int fwb = t & 192;  // wave-uniform LDS base part
  const int fx = fr & 7;    // read-side XOR key

#define ISSUE_KV(ntt_, buf_)                                                   \
  do {                                                                         \
    const u16* Kb = Kh + (size_t)(ntt_)*64 * DP;                               \
    const u16* Vb = Vh + (ntt_)*64;                                            \
    _Pragma("unroll") for (int i = 0; i < 2; i++) {                            \
      int f = i * 256 + t;                                                     \
      int r = f >> 3, sl = (f & 7) ^ (r & 7);                                  \
      gload_lds16(Kb + (size_t)r * DP + sl * 8,                                \
                  &KVs[buf_][0][(i * 256 + fwb) * 8]);                         \
      gload_lds16(Vb + (size_t)r * N_ + sl * 8,                                \
                  &KVs[buf_][1][(i * 256 + fwb) * 8]);                         \
    }                                                                          \
  } while (0)

  // per-half tile ranges for this split
  const int s0 = p, s1 = 127 - p;
  const int ntf0 = (s0 >> 2) + 1, ntf1 = (s1 >> 2) + 1;
  const int lo0 = sg ? (ntf0 >> 1) : 0, hi0 = sg ? ntf0 : (ntf0 >> 1);
  const int lo1 = sg ? (ntf1 >> 1) : 0, hi1 = sg ? ntf1 : (ntf1 >> 1);

  int bi = 0;
  if (hi0 > lo0) {
    ISSUE_KV(lo0, 0);
  } else if (hi1 > lo1) {
    ISSUE_KV(lo1, 0);
  }

  for (int half = 0; half < 2; ++half) {
    const int s = half ? s1 : s0;
    const int ntf = half ? ntf1 : ntf0;
    const int lo = half ? lo1 : lo0, hi = half ? hi1 : hi0;

    // Q fragments from fragment-major Qf: tile s>>2, ifr = s&3
    bf16x8 qf[2];
#pragma unroll
    for (int kk = 0; kk < 2; kk++)
      qf[kk] = *(const bf16x8*)(Qfh + ((size_t)(s >> 2) * 512 +
                                       ((s & 3) * 2 + kk) * 64 +
                                       fg * 16 + fr) * 8);

    f32x4 oacc[4] = {};
    float l_lane = 0.f;  // per-lane partial row sum (qrow = fr)

    for (int tt = lo; tt < hi; ++tt) {
      drain_vmem();     // r24: THIS wave's staged loads definitely landed
      __syncthreads();  // all waves' loads landed; all done with buf^1
      {
        int ntt = -1;
        if (tt + 1 < hi) ntt = tt + 1;
        else if (half == 0 && hi1 > lo1) ntt = lo1;
        if (ntt >= 0) {
          ISSUE_KV(ntt, bi ^ 1);
        }
      }

      // Swapped QK^T: sacc[jf] = K_jf · Q^T ; lane: qrow=fr, kv=jf*16+fg*4+r
      f32x4 sacc[4] = {};
#pragma unroll
      for (int kk = 0; kk < 2; kk++) {
        bf16x8 bk[4];
#pragma unroll
        for (int jf = 0; jf < 4; jf++)
          bk[jf] = *(const bf16x8*)&KVs[bi][0][(jf * 16 + fr) * 64 +
                                               ((kk * 4 + fg) ^ fx) * 8];
#pragma unroll
        for (int jf = 0; jf < 4; jf++)
          sacc[jf] = __builtin_amdgcn_mfma_f32_16x16x32_bf16(
              bk[jf], qf[kk], sacc[jf], 0, 0, 0);
      }

      // exp2 + mask + pack P IN REGISTERS (A-operand of 16x16x16 PV)
      bf16x4 pa[4];
      if (tt == ntf - 1) {
        const int gi = s * 16 + fr;  // qrow
#pragma unroll
        for (int jf = 0; jf < 4; jf++) {
          float pv[4];
#pragma unroll
          for (int r = 0; r < 4; r++) {
            int gj = tt * 64 + jf * 16 + fg * 4 + r;  // kv
            pv[r] = (gj <= gi) ? EXP2F(sacc[jf][r]) : 0.f;
            l_lane += pv[r];
          }
          uint2 pk = {cvtpk_bf16(pv[0], pv[1]), cvtpk_bf16(pv[2], pv[3])};
          pa[jf] = __builtin_bit_cast(bf16x4, pk);
        }
      } else {
#pragma unroll
        for (int jf = 0; jf < 4; jf++) {
          float pv[4];
#pragma unroll
          for (int r = 0; r < 4; r++) {
            pv[r] = EXP2F(sacc[jf][r]);
            l_lane += pv[r];
          }
          uint2 pk = {cvtpk_bf16(pv[0], pv[1]), cvtpk_bf16(pv[2], pv[3])};
          pa[jf] = __builtin_bit_cast(bf16x4, pk);
        }
      }

      // P @ V via 16x16x16 (K=16 per jf block); V from LDS as b64 reads
#pragma unroll
      for (int df = 0; df < 4; df++) {
        const int vrow = (df * 16 + fr) * 64;  // Vs row = d
#pragma unroll
        for (int jf = 0; jf < 4; jf++) {
          bf16x4 bv = *(const bf16x4*)&KVs[bi][1][vrow +
                                                  (((jf * 2 + (fg >> 1)) ^ fx) * 8) +
                                                  (fg & 1) * 4];
          oacc[df] = __builtin_amdgcn_mfma_f32_16x16x16bf16_1k(
              pa[jf], bv, oacc[df], 0, 0, 0);
        }
      }
      bi ^= 1;
    }

    // epilogue: raw partial sums (no normalization — combine happens in ln)
    {
      float v = l_lane;
      v += __shfl_xor(v, 16);
      v += __shfl_xor(v, 32);
      const size_t obase = (((size_t)(sg * 2 + b) * 16 + h) * 2048 + s * 16);
      if (fg == 0) lp[obase + fr] = v;  // lane holds l for qrow = fr
#pragma unroll
      for (int df = 0; df < 4; df++) {
        int d = df * 16 + fr;
        if (d < D_) {
#pragma unroll
          for (int r = 0; r < 4; r++)
            Op[(obase + fg * 4 + r) * 56 + d] = f2bf(oacc[df][r]);
        }
      }
    }
    l_lane = 0.f;
  }
}

// ---------------------------------------------------------------------------
// Pass B: attention-weight column means via transposed scores T = K*Q^T.
// Paired strips (p, 63-p) per block (causal load-balance); Q fragments from
// fragment-major Qf; XCD-grouping swizzle; grid 1024. No async staging.
// ---------------------------------------------------------------------------
struct QTile {
  bf16x8 q[4][2];
  float li[4];
};

#define LOADQ(dst, rt_)                                                        \
  {                                                                            \
    _Pragma("unroll") for (int ifr = 0; ifr < 4; ifr++) {                      \
      _Pragma("unroll") for (int kk = 0; kk < 2; kk++)                         \
          dst.q[ifr][kk] = *(const bf16x8*)(Qfh +                              \
              ((((size_t)(rt_)*4 + ifr) * 2 + kk) * 64 + fg * 16 + fr) * 8);   \
      dst.li[ifr] = linv_h[(rt_)*64 + ifr * 16 + fr];                          \
    }                                                                          \
  }

#define COMPUTET(src, rt_)                                                     \
  {                                                                            \
    f32x4 tacc[2][4] = {};                                                     \
    _Pragma("unroll") for (int kk = 0; kk < 2; kk++)                           \
        _Pragma("unroll") for (int jm = 0; jm < 2; jm++)                       \
        _Pragma("unroll") for (int ifr = 0; ifr < 4; ifr++)                    \
            tacc[jm][ifr] = __builtin_amdgcn_mfma_f32_16x16x32_bf16(           \
                kf[jm][kk], src.q[ifr][kk], tacc[jm][ifr], 0, 0, 0);           \
    if ((rt_) == rt0) {                                                        \
      _Pragma("unroll") for (int jm = 0; jm < 2; jm++)                         \
          _Pragma("unroll") for (int ifr = 0; ifr < 4; ifr++)                  \
          _Pragma("unroll") for (int r = 0; r < 4; r++) {                      \
        int gi = (rt_)*64 + ifr * 16 + fr;                                     \
        int gj = ct * 32 + jm * 16 + fg * 4 + r;                               \
        if (gi >= gj)                                                          \
          s_acc[jm][r] += EXP2F(tacc[jm][ifr][r]) * src.li[ifr];               \
      }                                                                        \
    } else {                                                                   \
      _Pragma("unroll") for (int jm = 0; jm < 2; jm++)                         \
          _Pragma("unroll") for (int ifr = 0; ifr < 4; ifr++)                  \
          _Pragma("unroll") for (int r = 0; r < 4; r++)                        \
              s_acc[jm][r] += EXP2F(tacc[jm][ifr][r]) * src.li[ifr];           \
    }                                                                          \
  }

__global__ __launch_bounds__(256) void attn_aw(const u16* __restrict__ Qf,
                                               const u16* __restrict__ Kp,
                                               const float* __restrict__ linv_g,
                                               float* __restrict__ aw) {
  // XCD-grouping swizzle (T1): all 32 p-blocks of one (h,b) on one XCD
  const int bid = blockIdx.x;
  const int xcd = bid & 7, idx = bid >> 3;
  const int g = xcd + 8 * (idx >> 5);  // 0..31 = b*16 + h
  const int p = idx & 31;
  const int b = g >> 4, h = g & 15;
  const int hk = h >> 2;
  const int t = threadIdx.x, w = t >> 6, lane = t & 63;
  const int fr = lane & 15, fg = lane >> 4;

  __shared__ float red[2][4][32];  // [half][wave][jm*16+fg*4+r]

  const u16* Qfh = Qf + (size_t)(b * HQ + h) * N_ * DP;  // fragment-major
  const u16* Kh = Kp + (size_t)(b * HK + hk) * N_ * DP;
  const float* linv_h = linv_g + (size_t)(b * HQ + h) * N_;

  for (int half = 0; half < 2; ++half) {
    const int ct = half ? (63 - p) : p;  // 32-col strip of T
    const int rt0 = ct >> 1;

    bf16x8 kf[2][2];
#pragma unroll
    for (int jm = 0; jm < 2; jm++)
#pragma unroll
      for (int kk = 0; kk < 2; kk++)
        kf[jm][kk] = *(const bf16x8*)(Kh + (size_t)(ct * 32 + jm * 16 + fr) * DP +
                                      kk * 32 + fg * 8);

    float s_acc[2][4] = {};
    QTile qa, qb;
    int rt = rt0 + w;  // wave-strided row loop
    if (rt <= 31) {
      LOADQ(qa, rt);
      while (true) {
        if (rt + 4 <= 31) LOADQ(qb, rt + 4);
        COMPUTET(qa, rt);
        rt += 4;
        if (rt > 31) break;
        if (rt + 4 <= 31) LOADQ(qa, rt + 4);
        COMPUTET(qb, rt);
        rt += 4;
        if (rt > 31) break;
      }
    }

    // cross-lane (fr) reduce, park wave-partials in LDS
#pragma unroll
    for (int jm = 0; jm < 2; jm++)
#pragma unroll
      for (int r = 0; r < 4; r++) {
        float v = s_acc[jm][r];
        v += __shfl_xor(v, 1);
        v += __shfl_xor(v, 2);
        v += __shfl_xor(v, 4);
        v += __shfl_xor(v, 8);
        if (fr == 0) red[half][w][jm * 16 + fg * 4 + r] = v;
      }
  }

  __syncthreads();
  if (w == 0 && fr == 0) {
#pragma unroll
    for (int half = 0; half < 2; ++half) {
      const int ct = half ? (63 - p) : p;
#pragma unroll
      for (int jm = 0; jm < 2; jm++)
#pragma unroll
        for (int r = 0; r < 4; r++) {
          int idx2 = jm * 16 + fg * 4 + r;
          float v = red[half][0][idx2] + red[half][1][idx2] +
                    red[half][2][idx2] + red[half][3][idx2];
          int gj = ct * 32 + jm * 16 + fg * 4 + r;
          aw[((size_t)b * N_ + gj) * HQ + h] = v * (1.0f / N_);
        }
    }
  }
}

// ---------------------------------------------------------------------------
// LayerNorm + kv-split COMBINE, one block per (b,n) row:
// x[h*56+d] = (Op0 + Op1) / (l0 + l1); also writes linv for attn_aw.
// bf16 output for the Wo GEMM.
// ---------------------------------------------------------------------------
__global__ __launch_bounds__(256) void ln_fwd(const u16* __restrict__ Op,
                                              const float* __restrict__ lp,
                                              const float* __restrict__ gamma,
                                              const float* __restrict__ beta,
                                              u16* __restrict__ out,
                                              float* __restrict__ linv_g) {
  const int row = blockIdx.x;
  const int b = row >> 11, n = row & 2047;
  const int t = threadIdx.x;
  __shared__ float lrec[16];
  __shared__ float red[8];

  if (t < 16) {
    float l0 = lp[((size_t)(0 + b) * 16 + t) * 2048 + n];
    float l1 = lp[((size_t)(2 + b) * 16 + t) * 2048 + n];
    float ri = 1.0f / (l0 + l1);
    lrec[t] = ri;
    linv_g[((size_t)b * 16 + t) * 2048 + n] = ri;
  }
  __syncthreads();

  float s = 0.f, s2 = 0.f;
  float v[4];
#pragma unroll
  for (int i = 0; i < 4; i++) {
    int c = t + 256 * i;
    if (c < EMBED) {
      int h = c / 56, d = c - h * 56;
      size_t o0 = (((size_t)(0 + b) * 16 + h) * 2048 + n) * 56 + d;
      size_t o1 = (((size_t)(2 + b) * 16 + h) * 2048 + n) * 56 + d;
      v[i] = (bf2f(Op[o0]) + bf2f(Op[o1])) * lrec[h];
    } else {
      v[i] = 0.f;
    }
    s += v[i];
    s2 += v[i] * v[i];
  }
#pragma unroll
  for (int m = 1; m <= 32; m <<= 1) {
    s += __shfl_xor(s, m);
    s2 += __shfl_xor(s2, m);
  }
  const int w = t >> 6, lane = t & 63;
  if (lane == 0) {
    red[w] = s;
    red[4 + w] = s2;
  }
  __syncthreads();
  s = red[0] + red[1] + red[2] + red[3];
  s2 = red[4] + red[5] + red[6] + red[7];
  const float mu = s * (1.0f / EMBED);
  const float var = s2 * (1.0f / EMBED) - mu * mu;
  const float rs = rsqrtf(var + 1e-5f);
#pragma unroll
  for (int i = 0; i < 4; i++) {
    int c = t + 256 * i;
    if (c < EMBED)
      out[(size_t)row * EMBED + c] = f2bf((v[i] - mu) * rs * gamma[c] + beta[c]);
  }
}

// ---------------------------------------------------------------------------
extern "C" void kernel_launch(void* const* d_in, const int* in_sizes, int n_in,
                              void* d_out, int out_size, void* d_ws,
                              size_t ws_size, hipStream_t stream) {
  (void)in_sizes; (void)n_in; (void)out_size; (void)ws_size;
  const float* query = (const float*)d_in[0];
  const float* key   = (const float*)d_in[1];
  const float* value = (const float*)d_in[2];
  const float* Wq    = (const float*)d_in[3];
  const float* Wk    = (const float*)d_in[4];
  const float* Wv    = (const float*)d_in[5];
  const float* Wo    = (const float*)d_in[6];
  const float* gamma = (const float*)d_in[7];
  const float* beta  = (const float*)d_in[8];

  float* out = (float*)d_out;                   // (b, n, EMBED) f32
  float* aw  = out + (size_t)B_ * N_ * EMBED;   // (b, s, HQ)   f32

  char* ws = (char*)d_ws;
  u16* Qf = (u16*)ws;        ws += (size_t)B_ * HQ * N_ * DP * 2;   // 8.39 MB
  u16* Kp = (u16*)ws;        ws += (size_t)B_ * HK * N_ * DP * 2;   // 2.10 MB
  u16* Vt = (u16*)ws;        ws += (size_t)B_ * HK * N_ * DP * 2;   // 2.10 MB
  float* linv = (float*)ws;  ws += (size_t)B_ * HQ * N_ * 4;        // 0.26 MB
  float* lp   = (float*)ws;  ws += (size_t)4 * HQ * N_ * 4;         // 0.52 MB
  u16* Wqb = (u16*)ws;       ws += (size_t)SEG_WQ * 2;              // 1.61 MB
  u16* Wkb = (u16*)ws;       ws += (size_t)SEG_WK * 2;              // 0.40 MB
  u16* Wvb = (u16*)ws;       ws += (size_t)SEG_WK * 2;              // 0.40 MB
  u16* Wob = (u16*)ws;       ws += (size_t)SEG_WQ * 2;              // 1.61 MB
  char* region = ws;         // 22.02 MB region, two lifetimes:
  u16* qb = (u16*)region;                        // phase 1: qb/kb/vb
  u16* kb = qb + (size_t)SEG_IN;
  u16* vb = kb + (size_t)SEG_IN;
  u16* Op  = (u16*)region;                       // phase 2: Op (14.68 MB)
  u16* LNo = Op + (size_t)4 * HQ * N_ * 56;      //          + LNo (7.34 MB)

  dim3 blk(256);
  const int M = B_ * N_;  // 4096

  pad_zero<<<dim3(384), blk, 0, stream>>>(Qf, Kp, Vt);  // 1.57MB

  to_bf16<<<dim3(3178), blk, 0, stream>>>(query, key, value, Wq, Wk, Wv, Wo,
                                          qb, kb, vb, Wqb, Wkb, Wvb, Wob);

  proj_gemm<<<dim3(M / 128, 22), blk, 0, stream>>>(qb, kb, vb, Wqb, Wkb, Wvb,
                                                   Qf, Kp, Vt);

  attn_fwd<<<dim3(64, HK, B_ * 2), blk, 0, stream>>>(Qf, Kp, Vt, Op, lp);
  ln_fwd<<<dim3(M), blk, 0, stream>>>(Op, lp, gamma, beta, LNo, linv);

  attn_aw<<<dim3(1024), blk, 0, stream>>>(Qf, Kp, linv, aw);
  gemm_wo<<<dim3(448), blk, 0, stream>>>(LNo, Wob, out);
}

// Round 25
// 119.783 us; speedup vs baseline: 1.0246x; 1.0021x over previous
//
#include <hip/hip_runtime.h>

#define B_    2
#define N_    2048
#define EMBED 896
#define HQ    16
#define HK    4
#define D_    56
#define DP    64

typedef unsigned short u16;
typedef unsigned int   u32;
typedef __attribute__((ext_vector_type(8))) short bf16x8;
typedef __attribute__((ext_vector_type(4))) short bf16x4;
typedef __attribute__((ext_vector_type(4))) float f32x4;

__device__ __forceinline__ u16 f2bf(float f) {
  u32 u = __builtin_bit_cast(u32, f);
  return (u16)((u + 0x7FFFu + ((u >> 16) & 1u)) >> 16);
}

__device__ __forceinline__ float bf2f(u16 x) {
  u32 u = (u32)x << 16;
  return __builtin_bit_cast(float, u);
}

// pack 2 f32 -> 2 bf16 in one u32 (RNE), single VALU op
__device__ __forceinline__ u32 cvtpk_bf16(float lo, float hi) {
  u32 r;
  asm("v_cvt_pk_bf16_f32 %0, %1, %2" : "=v"(r) : "v"(lo), "v"(hi));
  return r;
}

#define EXP2F(x) __builtin_amdgcn_exp2f(x)

// Async global->LDS, 16B per lane. LDS dest is wave-uniform base + lane*16.
__device__ __forceinline__ void gload_lds16(const u16* g, u16* l) {
  __builtin_amdgcn_global_load_lds(
      (const __attribute__((address_space(1))) void*)g,
      (__attribute__((address_space(3))) void*)l, 16, 0, 0);
}

// Explicit drain of THIS wave's outstanding async loads before the barrier
// (closes the r23 intermittent stale-LDS-read race; no-op if compiler
// already emits vmcnt(0) for __syncthreads).
__device__ __forceinline__ void drain_vmem() {
  asm volatile("s_waitcnt vmcnt(0)" ::: "memory");
}

// QSCALE = (1/sqrt(56)) * log2(e); folded into Q so softmax uses exp2
#define QSCALE 0.19278822f

// ---------------------------------------------------------------------------
// Zero pad lanes: Qf fragment-major pad chunks (cols 56..63 = kk=1, fg=3),
// Kp rows d=56..63, Vt pad stripes. 1.57 MB, one int4/thread.
// ---------------------------------------------------------------------------
__global__ __launch_bounds__(256) void pad_zero(u16* __restrict__ Qf,
                                                u16* __restrict__ Kp,
                                                u16* __restrict__ Vt) {
  int i = blockIdx.x * 256 + threadIdx.x;  // 0..98303
  int4 z = {0, 0, 0, 0};
  if (i < 65536) {                       // Qf pad chunks: 1024 tiles x 4 ifr x 16 fr
    int tile = i >> 6, ifr = (i >> 4) & 3, fr = i & 15;
    *(int4*)(Qf + (size_t)tile * 4096 +
             ((((ifr * 2 + 1) * 4 + 3) * 16) + fr) * 8) = z;
  } else if (i < 81920) {                // Kp rows (b*HK*N)
    *(int4*)(Kp + (size_t)(i - 65536) * 64 + 56) = z;
  } else {                               // Vt pad stripes: 8 x (8 rows x 2048)
    int j = i - 81920;                   // 0..16383
    int bhk = j >> 11;                   // 0..7
    int off = j & 2047;                  // int4 index within stripe
    *(int4*)(Vt + ((size_t)bhk * 64 + 56) * 2048 + (size_t)off * 8) = z;
  }
}

// ---------------------------------------------------------------------------
// Bulk f32 -> bf16 conversion. r25: 8 float4/thread (ILP=8) — round-24
// counters showed 2.4 TB/s vs 6.3 ceiling, latency-bound (VALUBusy 3.7%).
// grid 1589 x 256 x 8 covers 3,254,272 float4s exactly.
// ---------------------------------------------------------------------------
#define SEG_IN  3670016u   // 2*2048*896
#define SEG_WQ  802816u    // 896*896
#define SEG_WK  200704u    // 224*896

__global__ __launch_bounds__(256) void to_bf16(
    const float* __restrict__ q, const float* __restrict__ k,
    const float* __restrict__ v, const float* __restrict__ wq,
    const float* __restrict__ wk, const float* __restrict__ wv,
    const float* __restrict__ wo, u16* __restrict__ qb, u16* __restrict__ kb,
    u16* __restrict__ vb, u16* __restrict__ wqb, u16* __restrict__ wkb,
    u16* __restrict__ wvb, u16* __restrict__ wob) {
  const size_t base = (size_t)blockIdx.x * 2048 + threadIdx.x;
  float4 v4[8];
  u16* dsts[8];
  size_t offs[8];
#pragma unroll
  for (int j = 0; j < 8; j++) {
    size_t e = (base + j * 256) * 4;
    const float* src;
    u16* dst;
    size_t off;
    if (e < SEG_IN)                  { src = q;  dst = qb;  off = e; }
    else if (e < 2 * (size_t)SEG_IN) { src = k;  dst = kb;  off = e - SEG_IN; }
    else if (e < 3 * (size_t)SEG_IN) { src = v;  dst = vb;  off = e - 2 * (size_t)SEG_IN; }
    else {
      size_t r = e - 3 * (size_t)SEG_IN;
      if (r < SEG_WQ)                   { src = wq; dst = wqb; off = r; }
      else if (r < SEG_WQ + SEG_WK)     { src = wk; dst = wkb; off = r - SEG_WQ; }
      else if (r < SEG_WQ + 2 * SEG_WK) { src = wv; dst = wvb; off = r - SEG_WQ - SEG_WK; }
      else                              { src = wo; dst = wob; off = r - SEG_WQ - 2 * SEG_WK; }
    }
    dsts[j] = dst; offs[j] = off;
    v4[j] = *(const float4*)(src + off);  // 8 independent loads in flight
  }
#pragma unroll
  for (int j = 0; j < 8; j++) {
    uint2 pb;
    pb.x = cvtpk_bf16(v4[j].x, v4[j].y);
    pb.y = cvtpk_bf16(v4[j].z, v4[j].w);
    *(uint2*)(dsts[j] + offs[j]) = pb;
  }
}

// ---------------------------------------------------------------------------
// GEMM core (m97 structure): BM=128, BN=64, BK=64, 256 thr. Single-buffer
// linear LDS staged via global_load_lds width=16. XOR swizzle both sides.
// Explicit vmcnt(0) drain before the staging barrier.
// ---------------------------------------------------------------------------
#define NT_K 14  // 896/64

#define GEMM_CORE(APTR, WPTR)                                                  \
  for (int it = 0; it < NT_K; ++it) {                                          \
    const int k0 = it * 64;                                                    \
    {                                                                          \
      const u16* Ag = (APTR) + (size_t)m0 * EMBED + k0;                        \
      _Pragma("unroll") for (int i = 0; i < 4; i++) {                          \
        int f = i * 256 + t;                                                   \
        int r = f >> 3, s = (f & 7) ^ (r & 7);                                 \
        gload_lds16(Ag + (size_t)r * EMBED + s * 8,                            \
                    AsL + (i * 256 + fwbase) * 8);                             \
      }                                                                        \
      const u16* Wg = (WPTR) + (size_t)wn0 * EMBED + k0;                       \
      _Pragma("unroll") for (int i = 0; i < 2; i++) {                          \
        int f = i * 256 + t;                                                   \
        int r = f >> 3, s = (f & 7) ^ (r & 7);                                 \
        gload_lds16(Wg + (size_t)r * EMBED + s * 8,                            \
                    BsL + (i * 256 + fwbase) * 8);                             \
      }                                                                        \
    }                                                                          \
    drain_vmem();                                                              \
    __syncthreads(); /* staged data visible to all waves */                    \
    _Pragma("unroll") for (int kk = 0; kk < 2; kk++) {                         \
      bf16x8 af[2], bfv[4];                                                    \
      _Pragma("unroll") for (int mf = 0; mf < 2; mf++) {                       \
        int ra = wr + mf * 16 + fr;                                            \
        af[mf] =                                                               \
            *(const bf16x8*)&AsL[ra * 64 + ((fg + kk * 4) ^ (ra & 7)) * 8];    \
      }                                                                        \
      _Pragma("unroll") for (int nf = 0; nf < 4; nf++) {                       \
        int rb = nf * 16 + fr;                                                 \
        bfv[nf] =                                                              \
            *(const bf16x8*)&BsL[rb * 64 + ((fg + kk * 4) ^ (rb & 7)) * 8];    \
      }                                                                        \
      _Pragma("unroll") for (int mf = 0; mf < 2; mf++)                         \
          _Pragma("unroll") for (int nf = 0; nf < 4; nf++)                     \
              acc[mf][nf] = __builtin_amdgcn_mfma_f32_16x16x32_bf16(           \
                  af[mf], bfv[nf], acc[mf][nf], 0, 0, 0);                      \
    }                                                                          \
    __syncthreads(); /* all waves done reading before next overwrite */       \
  }

// Fused QKV projection. 2D grid (32,22). Q scatters directly into
// fragment-major Qf.
__global__ __launch_bounds__(256) void proj_gemm(
    const u16* __restrict__ qb, const u16* __restrict__ kb,
    const u16* __restrict__ vb, const u16* __restrict__ Wqb,
    const u16* __restrict__ Wkb, const u16* __restrict__ Wvb,
    u16* __restrict__ Qf, u16* __restrict__ Kp, u16* __restrict__ Vt) {
  __shared__ __align__(16) u16 lds[12288];  // AsL 128x64 | BsL 64x64
  u16* AsL = lds;
  u16* BsL = lds + 8192;
  const int t = threadIdx.x;
  const int m0 = blockIdx.x * 128;
  const int y = blockIdx.y;
  int p, nt;
  if (y < 14)      { p = 0; nt = y; }
  else if (y < 18) { p = 1; nt = y - 14; }
  else             { p = 2; nt = y - 18; }
  const u16* A = p == 0 ? qb : (p == 1 ? kb : vb);
  const u16* W = p == 0 ? Wqb : (p == 1 ? Wkb : Wvb);
  const int Nproj = p == 0 ? 896 : 224;
  const int wn0 = nt * 64;

  const int w = t >> 6, lane = t & 63;
  const int fr = lane & 15, fg = lane >> 4;
  const int wr = w * 32;
  const int fwbase = t & 192;  // w*64, wave-uniform

  f32x4 acc[2][4] = {};

  GEMM_CORE(A, W)

  if (p == 0) {
    // Q: scatter into fragment-major Qf with QSCALE
#pragma unroll
    for (int nf = 0; nf < 4; nf++) {
      int col = wn0 + nf * 16 + fr;  // < 896 always
      int hh = col / 56, d = col - hh * 56;
      int kkq = d >> 5, fgq = (d & 31) >> 3, c7 = d & 7;
#pragma unroll
      for (int mf = 0; mf < 2; mf++)
#pragma unroll
        for (int r = 0; r < 4; r++) {
          int row = m0 + wr + mf * 16 + fg * 4 + r;
          int bb = row >> 11, nn = row & 2047;
          int tile = (bb * 16 + hh) * 32 + (nn >> 6);
          int irow = nn & 63, ifr = irow >> 4, frq = irow & 15;
          Qf[(size_t)tile * 4096 +
             ((((ifr * 2 + kkq) * 4 + fgq) * 16) + frq) * 8 + c7] =
              f2bf(acc[mf][nf][r] * QSCALE);
        }
    }
  } else if (p == 1) {
#pragma unroll
    for (int nf = 0; nf < 4; nf++) {
      int col = wn0 + nf * 16 + fr;
      if (col < Nproj) {
        int hh = col / 56, d = col - hh * 56;
#pragma unroll
        for (int mf = 0; mf < 2; mf++)
#pragma unroll
          for (int r = 0; r < 4; r++) {
            int row = m0 + wr + mf * 16 + fg * 4 + r;
            int bb = row >> 11, nn = row & 2047;
            Kp[((size_t)((bb * 4 + hh) * 2048 + nn)) * 64 + d] =
                f2bf(acc[mf][nf][r]);
          }
      }
    }
  } else {
    // V: transpose through LDS (reuse staging buffer), coalesced int4 stores
    u16* Traw = lds;  // need 64*136 = 8704 <= 12288
#define TS(r_, c_) Traw[(r_)*136 + (c_)]
#pragma unroll
    for (int nf = 0; nf < 4; nf++)
#pragma unroll
      for (int mf = 0; mf < 2; mf++)
#pragma unroll
        for (int r = 0; r < 4; r++)
          TS(nf * 16 + fr, wr + mf * 16 + fg * 4 + r) = f2bf(acc[mf][nf][r]);
    __syncthreads();
    const int bb = m0 >> 11, n_base = m0 & 2047;
#pragma unroll
    for (int i = 0; i < 4; i++) {
      int flat = i * 256 + t;     // 0..1023
      int dr = flat >> 4;         // 0..63 (local V col)
      int c8 = (flat & 15) * 8;   // 0..120 (local row)
      int col = wn0 + dr;
      if (col < 224) {
        int hh = col / 56, d = col - hh * 56;
        *(int4*)(Vt + ((size_t)((bb * 4 + hh) * 64 + d)) * 2048 + n_base + c8) =
            *(int4*)&TS(dr, c8);
      }
    }
  }
}

// Output projection: out = LNo (bf16) @ Wo^T. 1D grid 448 = 8 XCD x 56,
// XCD-grouping swizzle (blocks sharing a W panel cluster per XCD).
__global__ __launch_bounds__(256) void gemm_wo(const u16* __restrict__ A,
                                               const u16* __restrict__ W,
                                               float* __restrict__ C) {
  __shared__ __align__(16) u16 lds[12288];
  u16* AsL = lds;
  u16* BsL = lds + 8192;
  const int t = threadIdx.x;
  const int bid = blockIdx.x;            // 0..447
  const int lin = (bid & 7) * 56 + (bid >> 3);
  const int m0 = (lin & 31) * 128;
  const int wn0 = (lin >> 5) * 64;       // panel 0..13
  const int w = t >> 6, lane = t & 63;
  const int fr = lane & 15, fg = lane >> 4;
  const int wr = w * 32;
  const int fwbase = t & 192;

  f32x4 acc[2][4] = {};

  GEMM_CORE(A, W)

#pragma unroll
  for (int nf = 0; nf < 4; nf++) {
    int col = wn0 + nf * 16 + fr;
#pragma unroll
    for (int mf = 0; mf < 2; mf++)
#pragma unroll
      for (int r = 0; r < 4; r++) {
        int row = m0 + wr + mf * 16 + fg * 4 + r;
        C[(size_t)row * EMBED + col] = acc[mf][nf][r];
      }
  }
}

// ---------------------------------------------------------------------------
// Pass A: causal flash attention, KV-SPLIT (S=2), SWAPPED QK^T (mfma(K,Q) =
// S^T): lane holds P[qrow=fr][kv=jf*16+fg*4+r] — the A-operand of
// v_mfma_f32_16x16x16_bf16 for PV. P never touches LDS. 32KB LDS.
// Q read from fragment-major Qf (coalesced chunk loads).
// Explicit vmcnt(0) drain before the per-tile barrier.
// ---------------------------------------------------------------------------
__global__ __launch_bounds__(256) void attn_fwd(const u16* __restrict__ Qf,
                                                const u16* __restrict__ Kp,
                                                const u16* __restrict__ Vt,
                                                u16* __restrict__ Op,
                                                float* __restrict__ lp) {
  const int p = blockIdx.x, hk = blockIdx.y;
  const int b = blockIdx.z >> 1, sg = blockIdx.z & 1;
  const int t = threadIdx.x, w = t >> 6, lane = t & 63;
  const int fr = lane & 15, fg = lane >> 4;
  const int h = hk * 4 + w;

  __shared__ __align__(16) u16 KVs[2][2][4096];  // [buf][K|V][64x64] 32KB

  const u16* Qfh = Qf + (size_t)(b * HQ + h) * N_ * DP;
  const u16* Kh = Kp + (size_t)(b * HK + hk) * N_ * DP;
  const u16* Vh = Vt + (size_t)(b * HK + hk) * DP * N_;

  const int fwb = t & 192;  // wave-uniform LDS base part
  const int fx = fr & 7;    // read-side XOR key

#define ISSUE_KV(ntt_, buf_)                                                   \
  do {                                                                         \
    const u16* Kb = Kh + (size_t)(ntt_)*64 * DP;                               \
    const u16* Vb = Vh + (ntt_)*64;                                            \
    _Pragma("unroll") for (int i = 0; i < 2; i++) {                            \
      int f = i * 256 + t;                                                     \
      int r = f >> 3, sl = (f & 7) ^ (r & 7);                                  \
      gload_lds16(Kb + (size_t)r * DP + sl * 8,                                \
                  &KVs[buf_][0][(i * 256 + fwb) * 8]);                         \
      gload_lds16(Vb + (size_t)r * N_ + sl * 8,                                \
                  &KVs[buf_][1][(i * 256 + fwb) * 8]);                         \
    }                                                                          \
  } while (0)

  // per-half tile ranges for this split
  const int s0 = p, s1 = 127 - p;
  const int ntf0 = (s0 >> 2) + 1, ntf1 = (s1 >> 2) + 1;
  const int lo0 = sg ? (ntf0 >> 1) : 0, hi0 = sg ? ntf0 : (ntf0 >> 1);
  const int lo1 = sg ? (ntf1 >> 1) : 0, hi1 = sg ? ntf1 : (ntf1 >> 1);

  int bi = 0;
  if (hi0 > lo0) {
    ISSUE_KV(lo0, 0);
  } else if (hi1 > lo1) {
    ISSUE_KV(lo1, 0);
  }

  for (int half = 0; half < 2; ++half) {
    const int s = half ? s1 : s0;
    const int ntf = half ? ntf1 : ntf0;
    const int lo = half ? lo1 : lo0, hi = half ? hi1 : hi0;

    // Q fragments from fragment-major Qf: tile s>>2, ifr = s&3
    bf16x8 qf[2];
#pragma unroll
    for (int kk = 0; kk < 2; kk++)
      qf[kk] = *(const bf16x8*)(Qfh + ((size_t)(s >> 2) * 512 +
                                       ((s & 3) * 2 + kk) * 64 +
                                       fg * 16 + fr) * 8);

    f32x4 oacc[4] = {};
    float l_lane = 0.f;  // per-lane partial row sum (qrow = fr)

    for (int tt = lo; tt < hi; ++tt) {
      drain_vmem();     // THIS wave's staged loads definitely landed
      __syncthreads();  // all waves' loads landed; all done with buf^1
      {
        int ntt = -1;
        if (tt + 1 < hi) ntt = tt + 1;
        else if (half == 0 && hi1 > lo1) ntt = lo1;
        if (ntt >= 0) {
          ISSUE_KV(ntt, bi ^ 1);
        }
      }

      // Swapped QK^T: sacc[jf] = K_jf · Q^T ; lane: qrow=fr, kv=jf*16+fg*4+r
      f32x4 sacc[4] = {};
#pragma unroll
      for (int kk = 0; kk < 2; kk++) {
        bf16x8 bk[4];
#pragma unroll
        for (int jf = 0; jf < 4; jf++)
          bk[jf] = *(const bf16x8*)&KVs[bi][0][(jf * 16 + fr) * 64 +
                                               ((kk * 4 + fg) ^ fx) * 8];
#pragma unroll
        for (int jf = 0; jf < 4; jf++)
          sacc[jf] = __builtin_amdgcn_mfma_f32_16x16x32_bf16(
              bk[jf], qf[kk], sacc[jf], 0, 0, 0);
      }

      // exp2 + mask + pack P IN REGISTERS (A-operand of 16x16x16 PV)
      bf16x4 pa[4];
      if (tt == ntf - 1) {
        const int gi = s * 16 + fr;  // qrow
#pragma unroll
        for (int jf = 0; jf < 4; jf++) {
          float pv[4];
#pragma unroll
          for (int r = 0; r < 4; r++) {
            int gj = tt * 64 + jf * 16 + fg * 4 + r;  // kv
            pv[r] = (gj <= gi) ? EXP2F(sacc[jf][r]) : 0.f;
            l_lane += pv[r];
          }
          uint2 pk = {cvtpk_bf16(pv[0], pv[1]), cvtpk_bf16(pv[2], pv[3])};
          pa[jf] = __builtin_bit_cast(bf16x4, pk);
        }
      } else {
#pragma unroll
        for (int jf = 0; jf < 4; jf++) {
          float pv[4];
#pragma unroll
          for (int r = 0; r < 4; r++) {
            pv[r] = EXP2F(sacc[jf][r]);
            l_lane += pv[r];
          }
          uint2 pk = {cvtpk_bf16(pv[0], pv[1]), cvtpk_bf16(pv[2], pv[3])};
          pa[jf] = __builtin_bit_cast(bf16x4, pk);
        }
      }

      // P @ V via 16x16x16 (K=16 per jf block); V from LDS as b64 reads
#pragma unroll
      for (int df = 0; df < 4; df++) {
        const int vrow = (df * 16 + fr) * 64;  // Vs row = d
#pragma unroll
        for (int jf = 0; jf < 4; jf++) {
          bf16x4 bv = *(const bf16x4*)&KVs[bi][1][vrow +
                                                  (((jf * 2 + (fg >> 1)) ^ fx) * 8) +
                                                  (fg & 1) * 4];
          oacc[df] = __builtin_amdgcn_mfma_f32_16x16x16bf16_1k(
              pa[jf], bv, oacc[df], 0, 0, 0);
        }
      }
      bi ^= 1;
    }

    // epilogue: raw partial sums (no normalization — combine happens in ln)
    {
      float v = l_lane;
      v += __shfl_xor(v, 16);
      v += __shfl_xor(v, 32);
      const size_t obase = (((size_t)(sg * 2 + b) * 16 + h) * 2048 + s * 16);
      if (fg == 0) lp[obase + fr] = v;  // lane holds l for qrow = fr
#pragma unroll
      for (int df = 0; df < 4; df++) {
        int d = df * 16 + fr;
        if (d < D_) {
#pragma unroll
          for (int r = 0; r < 4; r++)
            Op[(obase + fg * 4 + r) * 56 + d] = f2bf(oacc[df][r]);
        }
      }
    }
    l_lane = 0.f;
  }
}

// ---------------------------------------------------------------------------
// Pass B: attention-weight column means via transposed scores T = K*Q^T.
// Paired strips (p, 63-p) per block (causal load-balance); Q fragments from
// fragment-major Qf; XCD-grouping swizzle; grid 1024. No async staging.
// ---------------------------------------------------------------------------
struct QTile {
  bf16x8 q[4][2];
  float li[4];
};

#define LOADQ(dst, rt_)                                                        \
  {                                                                            \
    _Pragma("unroll") for (int ifr = 0; ifr < 4; ifr++) {                      \
      _Pragma("unroll") for (int kk = 0; kk < 2; kk++)                         \
          dst.q[ifr][kk] = *(const bf16x8*)(Qfh +                              \
              ((((size_t)(rt_)*4 + ifr) * 2 + kk) * 64 + fg * 16 + fr) * 8);   \
      dst.li[ifr] = linv_h[(rt_)*64 + ifr * 16 + fr];                          \
    }                                                                          \
  }

#define COMPUTET(src, rt_)                                                     \
  {                                                                            \
    f32x4 tacc[2][4] = {};                                                     \
    _Pragma("unroll") for (int kk = 0; kk < 2; kk++)                           \
        _Pragma("unroll") for (int jm = 0; jm < 2; jm++)                       \
        _Pragma("unroll") for (int ifr = 0; ifr < 4; ifr++)                    \
            tacc[jm][ifr] = __builtin_amdgcn_mfma_f32_16x16x32_bf16(           \
                kf[jm][kk], src.q[ifr][kk], tacc[jm][ifr], 0, 0, 0);           \
    if ((rt_) == rt0) {                                                        \
      _Pragma("unroll") for (int jm = 0; jm < 2; jm++)                         \
          _Pragma("unroll") for (int ifr = 0; ifr < 4; ifr++)                  \
          _Pragma("unroll") for (int r = 0; r < 4; r++) {                      \
        int gi = (rt_)*64 + ifr * 16 + fr;                                     \
        int gj = ct * 32 + jm * 16 + fg * 4 + r;                               \
        if (gi >= gj)                                                          \
          s_acc[jm][r] += EXP2F(tacc[jm][ifr][r]) * src.li[ifr];               \
      }                                                                        \
    } else {                                                                   \
      _Pragma("unroll") for (int jm = 0; jm < 2; jm++)                         \
          _Pragma("unroll") for (int ifr = 0; ifr < 4; ifr++)                  \
          _Pragma("unroll") for (int r = 0; r < 4; r++)                        \
              s_acc[jm][r] += EXP2F(tacc[jm][ifr][r]) * src.li[ifr];           \
    }                                                                          \
  }

__global__ __launch_bounds__(256) void attn_aw(const u16* __restrict__ Qf,
                                               const u16* __restrict__ Kp,
                                               const float* __restrict__ linv_g,
                                               float* __restrict__ aw) {
  // XCD-grouping swizzle (T1): all 32 p-blocks of one (h,b) on one XCD
  const int bid = blockIdx.x;
  const int xcd = bid & 7, idx = bid >> 3;
  const int g = xcd + 8 * (idx >> 5);  // 0..31 = b*16 + h
  const int p = idx & 31;
  const int b = g >> 4, h = g & 15;
  const int hk = h >> 2;
  const int t = threadIdx.x, w = t >> 6, lane = t & 63;
  const int fr = lane & 15, fg = lane >> 4;

  __shared__ float red[2][4][32];  // [half][wave][jm*16+fg*4+r]

  const u16* Qfh = Qf + (size_t)(b * HQ + h) * N_ * DP;  // fragment-major
  const u16* Kh = Kp + (size_t)(b * HK + hk) * N_ * DP;
  const float* linv_h = linv_g + (size_t)(b * HQ + h) * N_;

  for (int half = 0; half < 2; ++half) {
    const int ct = half ? (63 - p) : p;  // 32-col strip of T
    const int rt0 = ct >> 1;

    bf16x8 kf[2][2];
#pragma unroll
    for (int jm = 0; jm < 2; jm++)
#pragma unroll
      for (int kk = 0; kk < 2; kk++)
        kf[jm][kk] = *(const bf16x8*)(Kh + (size_t)(ct * 32 + jm * 16 + fr) * DP +
                                      kk * 32 + fg * 8);

    float s_acc[2][4] = {};
    QTile qa, qb;
    int rt = rt0 + w;  // wave-strided row loop
    if (rt <= 31) {
      LOADQ(qa, rt);
      while (true) {
        if (rt + 4 <= 31) LOADQ(qb, rt + 4);
        COMPUTET(qa, rt);
        rt += 4;
        if (rt > 31) break;
        if (rt + 4 <= 31) LOADQ(qa, rt + 4);
        COMPUTET(qb, rt);
        rt += 4;
        if (rt > 31) break;
      }
    }

    // cross-lane (fr) reduce, park wave-partials in LDS
#pragma unroll
    for (int jm = 0; jm < 2; jm++)
#pragma unroll
      for (int r = 0; r < 4; r++) {
        float v = s_acc[jm][r];
        v += __shfl_xor(v, 1);
        v += __shfl_xor(v, 2);
        v += __shfl_xor(v, 4);
        v += __shfl_xor(v, 8);
        if (fr == 0) red[half][w][jm * 16 + fg * 4 + r] = v;
      }
  }

  __syncthreads();
  if (w == 0 && fr == 0) {
#pragma unroll
    for (int half = 0; half < 2; ++half) {
      const int ct = half ? (63 - p) : p;
#pragma unroll
      for (int jm = 0; jm < 2; jm++)
#pragma unroll
        for (int r = 0; r < 4; r++) {
          int idx2 = jm * 16 + fg * 4 + r;
          float v = red[half][0][idx2] + red[half][1][idx2] +
                    red[half][2][idx2] + red[half][3][idx2];
          int gj = ct * 32 + jm * 16 + fg * 4 + r;
          aw[((size_t)b * N_ + gj) * HQ + h] = v * (1.0f / N_);
        }
    }
  }
}

// ---------------------------------------------------------------------------
// LayerNorm + kv-split COMBINE, one block per (b,n) row:
// x[h*56+d] = (Op0 + Op1) / (l0 + l1); also writes linv for attn_aw.
// bf16 output for the Wo GEMM.
// ---------------------------------------------------------------------------
__global__ __launch_bounds__(256) void ln_fwd(const u16* __restrict__ Op,
                                              const float* __restrict__ lp,
                                              const float* __restrict__ gamma,
                                              const float* __restrict__ beta,
                                              u16* __restrict__ out,
                                              float* __restrict__ linv_g) {
  const int row = blockIdx.x;
  const int b = row >> 11, n = row & 2047;
  const int t = threadIdx.x;
  __shared__ float lrec[16];
  __shared__ float red[8];

  if (t < 16) {
    float l0 = lp[((size_t)(0 + b) * 16 + t) * 2048 + n];
    float l1 = lp[((size_t)(2 + b) * 16 + t) * 2048 + n];
    float ri = 1.0f / (l0 + l1);
    lrec[t] = ri;
    linv_g[((size_t)b * 16 + t) * 2048 + n] = ri;
  }
  __syncthreads();

  float s = 0.f, s2 = 0.f;
  float v[4];
#pragma unroll
  for (int i = 0; i < 4; i++) {
    int c = t + 256 * i;
    if (c < EMBED) {
      int h = c / 56, d = c - h * 56;
      size_t o0 = (((size_t)(0 + b) * 16 + h) * 2048 + n) * 56 + d;
      size_t o1 = (((size_t)(2 + b) * 16 + h) * 2048 + n) * 56 + d;
      v[i] = (bf2f(Op[o0]) + bf2f(Op[o1])) * lrec[h];
    } else {
      v[i] = 0.f;
    }
    s += v[i];
    s2 += v[i] * v[i];
  }
#pragma unroll
  for (int m = 1; m <= 32; m <<= 1) {
    s += __shfl_xor(s, m);
    s2 += __shfl_xor(s2, m);
  }
  const int w = t >> 6, lane = t & 63;
  if (lane == 0) {
    red[w] = s;
    red[4 + w] = s2;
  }
  __syncthreads();
  s = red[0] + red[1] + red[2] + red[3];
  s2 = red[4] + red[5] + red[6] + red[7];
  const float mu = s * (1.0f / EMBED);
  const float var = s2 * (1.0f / EMBED) - mu * mu;
  const float rs = rsqrtf(var + 1e-5f);
#pragma unroll
  for (int i = 0; i < 4; i++) {
    int c = t + 256 * i;
    if (c < EMBED)
      out[(size_t)row * EMBED + c] = f2bf((v[i] - mu) * rs * gamma[c] + beta[c]);
  }
}

// ---------------------------------------------------------------------------
extern "C" void kernel_launch(void* const* d_in, const int* in_sizes, int n_in,
                              void* d_out, int out_size, void* d_ws,
                              size_t ws_size, hipStream_t stream) {
  (void)in_sizes; (void)n_in; (void)out_size; (void)ws_size;
  const float* query = (const float*)d_in[0];
  const float* key   = (const float*)d_in[1];
  const float* value = (const float*)d_in[2];
  const float* Wq    = (const float*)d_in[3];
  const float* Wk    = (const float*)d_in[4];
  const float* Wv    = (const float*)d_in[5];
  const float* Wo    = (const float*)d_in[6];
  const float* gamma = (const float*)d_in[7];
  const float* beta  = (const float*)d_in[8];

  float* out = (float*)d_out;                   // (b, n, EMBED) f32
  float* aw  = out + (size_t)B_ * N_ * EMBED;   // (b, s, HQ)   f32

  char* ws = (char*)d_ws;
  u16* Qf = (u16*)ws;        ws += (size_t)B_ * HQ * N_ * DP * 2;   // 8.39 MB
  u16* Kp = (u16*)ws;        ws += (size_t)B_ * HK * N_ * DP * 2;   // 2.10 MB
  u16* Vt = (u16*)ws;        ws += (size_t)B_ * HK * N_ * DP * 2;   // 2.10 MB
  float* linv = (float*)ws;  ws += (size_t)B_ * HQ * N_ * 4;        // 0.26 MB
  float* lp   = (float*)ws;  ws += (size_t)4 * HQ * N_ * 4;         // 0.52 MB
  u16* Wqb = (u16*)ws;       ws += (size_t)SEG_WQ * 2;              // 1.61 MB
  u16* Wkb = (u16*)ws;       ws += (size_t)SEG_WK * 2;              // 0.40 MB
  u16* Wvb = (u16*)ws;       ws += (size_t)SEG_WK * 2;              // 0.40 MB
  u16* Wob = (u16*)ws;       ws += (size_t)SEG_WQ * 2;              // 1.61 MB
  char* region = ws;         // 22.02 MB region, two lifetimes:
  u16* qb = (u16*)region;                        // phase 1: qb/kb/vb
  u16* kb = qb + (size_t)SEG_IN;
  u16* vb = kb + (size_t)SEG_IN;
  u16* Op  = (u16*)region;                       // phase 2: Op (14.68 MB)
  u16* LNo = Op + (size_t)4 * HQ * N_ * 56;      //          + LNo (7.34 MB)

  dim3 blk(256);
  const int M = B_ * N_;  // 4096

  pad_zero<<<dim3(384), blk, 0, stream>>>(Qf, Kp, Vt);  // 1.57MB

  to_bf16<<<dim3(1589), blk, 0, stream>>>(query, key, value, Wq, Wk, Wv, Wo,
                                          qb, kb, vb, Wqb, Wkb, Wvb, Wob);

  proj_gemm<<<dim3(M / 128, 22), blk, 0, stream>>>(qb, kb, vb, Wqb, Wkb, Wvb,
                                                   Qf, Kp, Vt);

  attn_fwd<<<dim3(64, HK, B_ * 2), blk, 0, stream>>>(Qf, Kp, Vt, Op, lp);
  ln_fwd<<<dim3(M), blk, 0, stream>>>(Op, lp, gamma, beta, LNo, linv);

  attn_aw<<<dim3(1024), blk, 0, stream>>>(Qf, Kp, linv, aw);
  gemm_wo<<<dim3(448), blk, 0, stream>>>(LNo, Wob, out);
}